// Round 1
// baseline (814.993 us; speedup 1.0000x reference)
//
#include <hip/hip_runtime.h>
#include <math.h>

#define LEAKY(x) ((x) > 0.f ? (x) : 0.01f * (x))

__global__ void zero_i32(int* p, int n) {
    int i = blockIdx.x * 256 + threadIdx.x;
    if (i < n) p[i] = 0;
}

__global__ void count_kernel(const int* __restrict__ dst, int* __restrict__ counts, int E) {
    int e = blockIdx.x * 256 + threadIdx.x;
    if (e < E) atomicAdd(&counts[dst[e]], 1);
}

__global__ void dis_kernel(const int* __restrict__ counts, float* __restrict__ dis, int n) {
    int i = blockIdx.x * 256 + threadIdx.x;
    if (i < n) dis[i] = rsqrtf((float)(counts[i] + 1));  // +1: self-loop
}

// Single-block chunked exclusive scan over counts -> row_ptr (and cursor copy).
__global__ void scan_kernel(const int* __restrict__ counts, int* __restrict__ row_ptr,
                            int* __restrict__ cursor, int n) {
    __shared__ int sm[1024];
    __shared__ int carry_s;
    if (threadIdx.x == 0) carry_s = 0;
    __syncthreads();
    int nb = (n + 1023) / 1024;
    for (int b = 0; b < nb; ++b) {
        int i = b * 1024 + threadIdx.x;
        int v = (i < n) ? counts[i] : 0;
        sm[threadIdx.x] = v;
        __syncthreads();
        int carry = carry_s;
        for (int off = 1; off < 1024; off <<= 1) {
            int t = (threadIdx.x >= off) ? sm[threadIdx.x - off] : 0;
            __syncthreads();
            sm[threadIdx.x] += t;
            __syncthreads();
        }
        int incl = sm[threadIdx.x];
        int excl = carry + incl - v;
        if (i < n) { row_ptr[i] = excl; cursor[i] = excl; }
        int total = carry + sm[1023];
        __syncthreads();
        if (threadIdx.x == 0) carry_s = total;
        __syncthreads();
    }
    if (threadIdx.x == 0) row_ptr[n] = carry_s;
}

__global__ void fill_kernel(const int* __restrict__ src, const int* __restrict__ dst,
                            int* __restrict__ cursor, int* __restrict__ edge_src, int E) {
    int e = blockIdx.x * 256 + threadIdx.x;
    if (e < E) {
        int pos = atomicAdd(&cursor[dst[e]], 1);
        edge_src[pos] = src[e];
    }
}

// A[i] = dis[i] * ( sum_{s in in(i)} dis[s]*X[s] + dis[i]*X[i] )   (self-loop folded in)
// One thread per (node, float4-chunk). KQ = K/4.
template <int KQ>
__global__ void agg_kernel(const float* __restrict__ X, const float* __restrict__ dis,
                           const int* __restrict__ row_ptr, const int* __restrict__ edge_src,
                           float* __restrict__ A, int n) {
    int id = blockIdx.x * 256 + threadIdx.x;
    int i = id / KQ, c = id % KQ;
    if (i >= n) return;
    const float4* X4 = (const float4*)X;
    float di = dis[i];
    float4 x = X4[(size_t)i * KQ + c];
    float4 acc;
    acc.x = di * x.x; acc.y = di * x.y; acc.z = di * x.z; acc.w = di * x.w;
    int e0 = row_ptr[i], e1 = row_ptr[i + 1];
    for (int e = e0; e < e1; ++e) {
        int s = edge_src[e];
        float ds = dis[s];
        float4 xs = X4[(size_t)s * KQ + c];
        acc.x += ds * xs.x; acc.y += ds * xs.y; acc.z += ds * xs.z; acc.w += ds * xs.w;
    }
    float4 o;
    o.x = di * acc.x; o.y = di * acc.y; o.z = di * acc.z; o.w = di * acc.w;
    ((float4*)A)[(size_t)i * KQ + c] = o;
}

// Xn[i,f] = leaky( sum_k A[i,k]*W[k,f] + b[f] ),  W row-major [K,96].
// 192 threads = (f in [0,96), g in {0,1}); 32 nodes/block, 16 rows per thread-group.
template <int K>
__global__ __launch_bounds__(192) void gemm_act_kernel(const float* __restrict__ A,
                                                       const float* __restrict__ W,
                                                       const float* __restrict__ b,
                                                       float* __restrict__ Xn, int n) {
    __shared__ __align__(16) float Wl[K * 96];
    __shared__ __align__(16) float Al[32][K];
    int tid = threadIdx.x;
    int f = tid % 96, g = tid / 96;
    for (int idx = tid; idx < K * 96; idx += 192) Wl[idx] = W[idx];
    int i0 = blockIdx.x * 32;
    for (int idx = tid; idx < 32 * K; idx += 192) {
        int r = idx / K, c = idx % K;
        int gi = i0 + r;
        Al[r][c] = (gi < n) ? A[(size_t)gi * K + c] : 0.f;
    }
    __syncthreads();
    float bf = b[f];
    float acc[16];
#pragma unroll
    for (int r = 0; r < 16; ++r) acc[r] = bf;
    for (int kc = 0; kc < K; kc += 16) {
        float wreg[16];
#pragma unroll
        for (int kk = 0; kk < 16; ++kk) wreg[kk] = Wl[(kc + kk) * 96 + f];
#pragma unroll
        for (int r = 0; r < 16; ++r) {
            const float4* arow = (const float4*)&Al[g * 16 + r][kc];
#pragma unroll
            for (int k4 = 0; k4 < 4; ++k4) {
                float4 a = arow[k4];
                acc[r] += a.x * wreg[k4 * 4 + 0] + a.y * wreg[k4 * 4 + 1] +
                          a.z * wreg[k4 * 4 + 2] + a.w * wreg[k4 * 4 + 3];
            }
        }
    }
#pragma unroll
    for (int r = 0; r < 16; ++r) {
        int gi = i0 + g * 16 + r;
        if (gi < n) {
            float v = acc[r];
            Xn[(size_t)gi * 96 + f] = LEAKY(v);
        }
    }
}

__device__ __forceinline__ int lower_bound(const int* b, int n, int v) {
    int lo = 0, hi = n;
    while (lo < hi) {
        int m = (lo + hi) >> 1;
        if (b[m] < v) lo = m + 1; else hi = m;
    }
    return lo;
}

// grid = G*8, block = 96. Chunked per-graph partial max/sum.
__global__ void pool_partial(const float* __restrict__ X, const int* __restrict__ batch,
                             float* __restrict__ pmax, float* __restrict__ psum, int n) {
    int g = blockIdx.x / 8, ch = blockIdx.x % 8;
    int f = threadIdx.x;
    int s = lower_bound(batch, n, g), e = lower_bound(batch, n, g + 1);
    int len = e - s;
    int cs = s + (int)((long)len * ch / 8);
    int ce = s + (int)((long)len * (ch + 1) / 8);
    float mx = -INFINITY, sm = 0.f;
    for (int i = cs; i < ce; ++i) {
        float v = X[(size_t)i * 96 + f];
        mx = fmaxf(mx, v);
        sm += v;
    }
    pmax[(size_t)blockIdx.x * 96 + f] = mx;
    psum[(size_t)blockIdx.x * 96 + f] = sm;
}

__global__ void pool_reduce(const float* __restrict__ pmax, const float* __restrict__ psum,
                            const int* __restrict__ batch, float* __restrict__ pooled, int n) {
    int g = blockIdx.x, f = threadIdx.x;
    float mx = -INFINITY, sm = 0.f;
    for (int c = 0; c < 8; ++c) {
        mx = fmaxf(mx, pmax[(size_t)(g * 8 + c) * 96 + f]);
        sm += psum[(size_t)(g * 8 + c) * 96 + f];
    }
    int s = lower_bound(batch, n, g), e = lower_bound(batch, n, g + 1);
    float cnt = fmaxf((float)(e - s), 1.f);
    pooled[g * 192 + f] = mx;
    pooled[g * 192 + 96 + f] = sm / cnt;
}

// out[g] = leaky(pooled[g]@Wo1 + bo1) @ Wo2 + bo2
__global__ void mlp_kernel(const float* __restrict__ pooled, const float* __restrict__ Wo1,
                           const float* __restrict__ bo1, const float* __restrict__ Wo2,
                           const float* __restrict__ bo2, float* __restrict__ out) {
    __shared__ float sh[96];
    int g = blockIdx.x, f = threadIdx.x;
    float acc = bo1[f];
    for (int k = 0; k < 192; ++k) acc += pooled[g * 192 + k] * Wo1[k * 96 + f];
    float a = LEAKY(acc);
    sh[f] = a * Wo2[f];
    __syncthreads();
    if (f == 0) {
        float sacc = 0.f;
        for (int k = 0; k < 96; ++k) sacc += sh[k];
        out[g] = sacc + bo2[0];
    }
}

extern "C" void kernel_launch(void* const* d_in, const int* in_sizes, int n_in,
                              void* d_out, int out_size, void* d_ws, size_t ws_size,
                              hipStream_t stream) {
    const float* x      = (const float*)d_in[0];
    const int*   eidx   = (const int*)d_in[1];
    const int*   batch  = (const int*)d_in[2];
    const float* W_init = (const float*)d_in[3];
    const float* b_init = (const float*)d_in[4];
    const float* W1 = (const float*)d_in[5];  const float* b1 = (const float*)d_in[6];
    const float* W2 = (const float*)d_in[7];  const float* b2 = (const float*)d_in[8];
    const float* W3 = (const float*)d_in[9];  const float* b3 = (const float*)d_in[10];
    const float* W4 = (const float*)d_in[11]; const float* b4 = (const float*)d_in[12];
    const float* Wo1 = (const float*)d_in[13]; const float* bo1 = (const float*)d_in[14];
    const float* Wo2 = (const float*)d_in[15]; const float* bo2 = (const float*)d_in[16];
    float* out = (float*)d_out;

    const int N = in_sizes[2];
    const int E = in_sizes[1] / 2;
    const int G = out_size;
    const int* src = eidx;
    const int* dst = eidx + E;

    char* ws = (char*)d_ws;
    size_t off = 0;
    auto alloc = [&](size_t bytes) {
        size_t o = off;
        off += (bytes + 255) & ~(size_t)255;
        return o;
    };
    float* dis     = (float*)(ws + alloc((size_t)N * 4));
    int*   counts  = (int*)(ws + alloc((size_t)N * 4));
    int*   row_ptr = (int*)(ws + alloc((size_t)(N + 1) * 4));
    int*   cursor  = (int*)(ws + alloc((size_t)N * 4));
    int*   edge_src= (int*)(ws + alloc((size_t)E * 4));
    float* B1      = (float*)(ws + alloc((size_t)N * 96 * 4));
    float* B2      = (float*)(ws + alloc((size_t)N * 96 * 4));
    float* pmax    = (float*)(ws + alloc((size_t)G * 8 * 96 * 4));
    float* psum    = (float*)(ws + alloc((size_t)G * 8 * 96 * 4));
    float* pooled  = (float*)(ws + alloc((size_t)G * 192 * 4));
    (void)ws_size; (void)n_in;

    zero_i32<<<(N + 255) / 256, 256, 0, stream>>>(counts, N);
    count_kernel<<<(E + 255) / 256, 256, 0, stream>>>(dst, counts, E);
    dis_kernel<<<(N + 255) / 256, 256, 0, stream>>>(counts, dis, N);
    scan_kernel<<<1, 1024, 0, stream>>>(counts, row_ptr, cursor, N);
    fill_kernel<<<(E + 255) / 256, 256, 0, stream>>>(src, dst, cursor, edge_src, E);

    // Layer 0: aggregate 16-wide input, then 16x96 GEMM.
    agg_kernel<4><<<((size_t)N * 4 + 255) / 256, 256, 0, stream>>>(x, dis, row_ptr, edge_src, B2, N);
    gemm_act_kernel<16><<<(N + 31) / 32, 192, 0, stream>>>(B2, W_init, b_init, B1, N);

    const float* Ws[4] = {W1, W2, W3, W4};
    const float* bs[4] = {b1, b2, b3, b4};
    for (int l = 0; l < 4; ++l) {
        agg_kernel<24><<<((size_t)N * 24 + 255) / 256, 256, 0, stream>>>(B1, dis, row_ptr, edge_src, B2, N);
        gemm_act_kernel<96><<<(N + 31) / 32, 192, 0, stream>>>(B2, Ws[l], bs[l], B1, N);
    }

    pool_partial<<<G * 8, 96, 0, stream>>>(B1, batch, pmax, psum, N);
    pool_reduce<<<G, 96, 0, stream>>>(pmax, psum, batch, pooled, N);
    mlp_kernel<<<G, 96, 0, stream>>>(pooled, Wo1, bo1, Wo2, bo2, out);
}

// Round 2
// 683.567 us; speedup vs baseline: 1.1923x; 1.1923x over previous
//
#include <hip/hip_runtime.h>
#include <math.h>

#define LEAKY(x) ((x) > 0.f ? (x) : 0.01f * (x))

__global__ void zero_i32(int* p, int n) {
    int i = blockIdx.x * 256 + threadIdx.x;
    if (i < n) p[i] = 0;
}

__global__ void count_kernel(const int* __restrict__ dst, int* __restrict__ counts, int E) {
    int e = blockIdx.x * 256 + threadIdx.x;
    if (e < E) atomicAdd(&counts[dst[e]], 1);
}

// Stage A: per-block (2048 elems) local exclusive scan into row_ptr, block sums
// into bsum, and dis = rsqrt(count+1) folded in.
__global__ __launch_bounds__(256) void scanA(const int* __restrict__ counts,
                                             int* __restrict__ row_ptr,
                                             int* __restrict__ bsum,
                                             float* __restrict__ dis, int n) {
    __shared__ int sm[256];
    int base = blockIdx.x * 2048 + threadIdx.x * 8;
    int v[8];
    int s = 0;
#pragma unroll
    for (int j = 0; j < 8; ++j) {
        int i = base + j;
        int c = (i < n) ? counts[i] : 0;
        v[j] = c;
        s += c;
        if (i < n) dis[i] = rsqrtf((float)(c + 1));  // +1: self-loop
    }
    sm[threadIdx.x] = s;
    __syncthreads();
    for (int off = 1; off < 256; off <<= 1) {
        int t = (threadIdx.x >= off) ? sm[threadIdx.x - off] : 0;
        __syncthreads();
        sm[threadIdx.x] += t;
        __syncthreads();
    }
    int excl = sm[threadIdx.x] - s;
#pragma unroll
    for (int j = 0; j < 8; ++j) {
        int i = base + j;
        if (i < n) row_ptr[i] = excl;
        excl += v[j];
    }
    if (threadIdx.x == 255) bsum[blockIdx.x] = sm[255];
}

// Stage B: single-wave exclusive scan of block sums (nb <= 64).
__global__ __launch_bounds__(64) void scanB(int* __restrict__ bsum, int nb) {
    __shared__ int sm[64];
    int v = (threadIdx.x < nb) ? bsum[threadIdx.x] : 0;
    sm[threadIdx.x] = v;
    __syncthreads();
    for (int off = 1; off < 64; off <<= 1) {
        int t = (threadIdx.x >= off) ? sm[threadIdx.x - off] : 0;
        __syncthreads();
        sm[threadIdx.x] += t;
        __syncthreads();
    }
    if (threadIdx.x < nb) bsum[threadIdx.x] = sm[threadIdx.x] - v;
}

// Stage C: add block offsets, copy to cursor, write row_ptr[n] = E.
__global__ void scanC(int* __restrict__ row_ptr, int* __restrict__ cursor,
                      const int* __restrict__ bsum, int n, int E) {
    int i = blockIdx.x * 256 + threadIdx.x;
    if (i < n) {
        int v = row_ptr[i] + bsum[i >> 11];
        row_ptr[i] = v;
        cursor[i] = v;
    }
    if (i == 0) row_ptr[n] = E;
}

// CSR fill; stores (src, dis[src]) packed so agg does a single 8B load per edge.
__global__ void fill_kernel(const int* __restrict__ src, const int* __restrict__ dst,
                            int* __restrict__ cursor, const float* __restrict__ dis,
                            uint2* __restrict__ edge_sw, int E) {
    int e = blockIdx.x * 256 + threadIdx.x;
    if (e < E) {
        int s = src[e];
        int pos = atomicAdd(&cursor[dst[e]], 1);
        edge_sw[pos] = make_uint2((unsigned)s, __float_as_uint(dis[s]));
    }
}

// A[i] = dis[i] * ( sum_{s in in(i)} dis[s]*X[s] + dis[i]*X[i] )
// One thread per (node, float4-chunk). KQ = K/4.
template <int KQ>
__global__ void agg_kernel(const float* __restrict__ X, const float* __restrict__ dis,
                           const int* __restrict__ row_ptr, const uint2* __restrict__ edge_sw,
                           float* __restrict__ A, int n) {
    int id = blockIdx.x * 256 + threadIdx.x;
    int i = id / KQ, c = id % KQ;
    if (i >= n) return;
    const float4* X4 = (const float4*)X;
    float di = dis[i];
    float4 x = X4[(size_t)i * KQ + c];
    float4 acc;
    acc.x = di * x.x; acc.y = di * x.y; acc.z = di * x.z; acc.w = di * x.w;
    int e0 = row_ptr[i], e1 = row_ptr[i + 1];
    for (int e = e0; e < e1; ++e) {
        uint2 ew = edge_sw[e];
        int s = (int)ew.x;
        float ds = __uint_as_float(ew.y);
        float4 xs = X4[(size_t)s * KQ + c];
        acc.x += ds * xs.x; acc.y += ds * xs.y; acc.z += ds * xs.z; acc.w += ds * xs.w;
    }
    float4 o;
    o.x = di * acc.x; o.y = di * acc.y; o.z = di * acc.z; o.w = di * acc.w;
    ((float4*)A)[(size_t)i * KQ + c] = o;
}

// Xn[i,f] = leaky( sum_k A[i,k]*W[k,f] + b[f] ),  W row-major [K,96].
// Block: 192 threads = 48 f-pairs x 4 row-groups; 64 nodes/block, 16 rows/thread,
// 2 f-columns/thread (halves LDS A-broadcast issue per FMA vs 1-f version).
template <int K>
__global__ __launch_bounds__(192) void gemm_act_kernel(const float* __restrict__ A,
                                                       const float* __restrict__ W,
                                                       const float* __restrict__ b,
                                                       float* __restrict__ Xn, int n) {
    constexpr int KQ = K / 4;
    __shared__ __align__(16) float Wl[K * 96];
    __shared__ __align__(16) float Al[64][K];
    int tid = threadIdx.x;
    int fh = tid % 48, g = tid / 48;  // f0 = 2*fh, rows g*16..g*16+15
    for (int idx = tid; idx < K * 96; idx += 192) Wl[idx] = W[idx];
    int i0 = blockIdx.x * 64;
    for (int idx = tid; idx < 64 * KQ; idx += 192) {
        int r = idx / KQ, c = idx % KQ;
        int gi = i0 + r;
        float4 val = (gi < n) ? ((const float4*)A)[(size_t)gi * KQ + c]
                              : make_float4(0.f, 0.f, 0.f, 0.f);
        ((float4*)&Al[r][0])[c] = val;
    }
    __syncthreads();
    int f0 = fh * 2;
    float2 bb = *(const float2*)&b[f0];
    float2 acc[16];
#pragma unroll
    for (int r = 0; r < 16; ++r) acc[r] = bb;
    for (int kc = 0; kc < K; kc += 16) {
        float2 w[16];
#pragma unroll
        for (int kk = 0; kk < 16; ++kk) w[kk] = *(const float2*)&Wl[(kc + kk) * 96 + f0];
#pragma unroll
        for (int r = 0; r < 16; ++r) {
            const float4* ar = (const float4*)&Al[g * 16 + r][kc];
#pragma unroll
            for (int k4 = 0; k4 < 4; ++k4) {
                float4 a = ar[k4];
                acc[r].x += a.x * w[4 * k4 + 0].x + a.y * w[4 * k4 + 1].x +
                            a.z * w[4 * k4 + 2].x + a.w * w[4 * k4 + 3].x;
                acc[r].y += a.x * w[4 * k4 + 0].y + a.y * w[4 * k4 + 1].y +
                            a.z * w[4 * k4 + 2].y + a.w * w[4 * k4 + 3].y;
            }
        }
    }
#pragma unroll
    for (int r = 0; r < 16; ++r) {
        int gi = i0 + g * 16 + r;
        if (gi < n) {
            float2 o;
            o.x = LEAKY(acc[r].x);
            o.y = LEAKY(acc[r].y);
            *(float2*)&Xn[(size_t)gi * 96 + f0] = o;
        }
    }
}

__device__ __forceinline__ int lower_bound(const int* b, int n, int v) {
    int lo = 0, hi = n;
    while (lo < hi) {
        int m = (lo + hi) >> 1;
        if (b[m] < v) lo = m + 1; else hi = m;
    }
    return lo;
}

// grid = G*8, block = 96. Chunked per-graph partial max/sum.
__global__ void pool_partial(const float* __restrict__ X, const int* __restrict__ batch,
                             float* __restrict__ pmax, float* __restrict__ psum, int n) {
    int g = blockIdx.x / 8, ch = blockIdx.x % 8;
    int f = threadIdx.x;
    int s = lower_bound(batch, n, g), e = lower_bound(batch, n, g + 1);
    int len = e - s;
    int cs = s + (int)((long)len * ch / 8);
    int ce = s + (int)((long)len * (ch + 1) / 8);
    float mx = -INFINITY, sm = 0.f;
    for (int i = cs; i < ce; ++i) {
        float v = X[(size_t)i * 96 + f];
        mx = fmaxf(mx, v);
        sm += v;
    }
    pmax[(size_t)blockIdx.x * 96 + f] = mx;
    psum[(size_t)blockIdx.x * 96 + f] = sm;
}

__global__ void pool_reduce(const float* __restrict__ pmax, const float* __restrict__ psum,
                            const int* __restrict__ batch, float* __restrict__ pooled, int n) {
    int g = blockIdx.x, f = threadIdx.x;
    float mx = -INFINITY, sm = 0.f;
    for (int c = 0; c < 8; ++c) {
        mx = fmaxf(mx, pmax[(size_t)(g * 8 + c) * 96 + f]);
        sm += psum[(size_t)(g * 8 + c) * 96 + f];
    }
    int s = lower_bound(batch, n, g), e = lower_bound(batch, n, g + 1);
    float cnt = fmaxf((float)(e - s), 1.f);
    pooled[g * 192 + f] = mx;
    pooled[g * 192 + 96 + f] = sm / cnt;
}

// out[g] = leaky(pooled[g]@Wo1 + bo1) @ Wo2 + bo2
__global__ void mlp_kernel(const float* __restrict__ pooled, const float* __restrict__ Wo1,
                           const float* __restrict__ bo1, const float* __restrict__ Wo2,
                           const float* __restrict__ bo2, float* __restrict__ out) {
    __shared__ float sh[96];
    int g = blockIdx.x, f = threadIdx.x;
    float acc = bo1[f];
    for (int k = 0; k < 192; ++k) acc += pooled[g * 192 + k] * Wo1[k * 96 + f];
    float a = LEAKY(acc);
    sh[f] = a * Wo2[f];
    __syncthreads();
    if (f == 0) {
        float sacc = 0.f;
        for (int k = 0; k < 96; ++k) sacc += sh[k];
        out[g] = sacc + bo2[0];
    }
}

extern "C" void kernel_launch(void* const* d_in, const int* in_sizes, int n_in,
                              void* d_out, int out_size, void* d_ws, size_t ws_size,
                              hipStream_t stream) {
    const float* x      = (const float*)d_in[0];
    const int*   eidx   = (const int*)d_in[1];
    const int*   batch  = (const int*)d_in[2];
    const float* W_init = (const float*)d_in[3];
    const float* b_init = (const float*)d_in[4];
    const float* W1 = (const float*)d_in[5];  const float* b1 = (const float*)d_in[6];
    const float* W2 = (const float*)d_in[7];  const float* b2 = (const float*)d_in[8];
    const float* W3 = (const float*)d_in[9];  const float* b3 = (const float*)d_in[10];
    const float* W4 = (const float*)d_in[11]; const float* b4 = (const float*)d_in[12];
    const float* Wo1 = (const float*)d_in[13]; const float* bo1 = (const float*)d_in[14];
    const float* Wo2 = (const float*)d_in[15]; const float* bo2 = (const float*)d_in[16];
    float* out = (float*)d_out;

    const int N = in_sizes[2];
    const int E = in_sizes[1] / 2;
    const int G = out_size;
    const int* src = eidx;
    const int* dst = eidx + E;

    char* ws = (char*)d_ws;
    size_t off = 0;
    auto alloc = [&](size_t bytes) {
        size_t o = off;
        off += (bytes + 255) & ~(size_t)255;
        return o;
    };
    float* dis     = (float*)(ws + alloc((size_t)N * 4));
    int*   counts  = (int*)(ws + alloc((size_t)N * 4));
    int*   row_ptr = (int*)(ws + alloc((size_t)(N + 1) * 4));
    int*   cursor  = (int*)(ws + alloc((size_t)N * 4));
    int*   bsum    = (int*)(ws + alloc(64 * 4));
    uint2* edge_sw = (uint2*)(ws + alloc((size_t)E * 8));
    float* B1      = (float*)(ws + alloc((size_t)N * 96 * 4));
    float* B2      = (float*)(ws + alloc((size_t)N * 96 * 4));
    float* pmax    = (float*)(ws + alloc((size_t)G * 8 * 96 * 4));
    float* psum    = (float*)(ws + alloc((size_t)G * 8 * 96 * 4));
    float* pooled  = (float*)(ws + alloc((size_t)G * 192 * 4));
    (void)ws_size; (void)n_in;

    const int nbScan = (N + 2047) / 2048;

    zero_i32<<<(N + 255) / 256, 256, 0, stream>>>(counts, N);
    count_kernel<<<(E + 255) / 256, 256, 0, stream>>>(dst, counts, E);
    scanA<<<nbScan, 256, 0, stream>>>(counts, row_ptr, bsum, dis, N);
    scanB<<<1, 64, 0, stream>>>(bsum, nbScan);
    scanC<<<(N + 255) / 256, 256, 0, stream>>>(row_ptr, cursor, bsum, N, E);
    fill_kernel<<<(E + 255) / 256, 256, 0, stream>>>(src, dst, cursor, dis, edge_sw, E);

    // Layer 0: aggregate 16-wide input, then 16x96 GEMM.
    agg_kernel<4><<<((size_t)N * 4 + 255) / 256, 256, 0, stream>>>(x, dis, row_ptr, edge_sw, B2, N);
    gemm_act_kernel<16><<<(N + 63) / 64, 192, 0, stream>>>(B2, W_init, b_init, B1, N);

    const float* Ws[4] = {W1, W2, W3, W4};
    const float* bs[4] = {b1, b2, b3, b4};
    for (int l = 0; l < 4; ++l) {
        agg_kernel<24><<<((size_t)N * 24 + 255) / 256, 256, 0, stream>>>(B1, dis, row_ptr, edge_sw, B2, N);
        gemm_act_kernel<96><<<(N + 63) / 64, 192, 0, stream>>>(B2, Ws[l], bs[l], B1, N);
    }

    pool_partial<<<G * 8, 96, 0, stream>>>(B1, batch, pmax, psum, N);
    pool_reduce<<<G, 96, 0, stream>>>(pmax, psum, batch, pooled, N);
    mlp_kernel<<<G, 96, 0, stream>>>(pooled, Wo1, bo1, Wo2, bo2, out);
}

// Round 3
// 548.390 us; speedup vs baseline: 1.4862x; 1.2465x over previous
//
#include <hip/hip_runtime.h>
#include <math.h>

#define LEAKY(x) ((x) > 0.f ? (x) : 0.01f * (x))

__global__ void zero_i32(int* p, int n) {
    int i = blockIdx.x * 256 + threadIdx.x;
    if (i < n) p[i] = 0;
}

__global__ void count_kernel(const int* __restrict__ dst, int* __restrict__ counts, int E) {
    int e = blockIdx.x * 256 + threadIdx.x;
    if (e < E) atomicAdd(&counts[dst[e]], 1);
}

// Stage A: per-block (2048 elems) local exclusive scan into row_ptr, block sums
// into bsum, and dis = rsqrt(count+1) folded in.
__global__ __launch_bounds__(256) void scanA(const int* __restrict__ counts,
                                             int* __restrict__ row_ptr,
                                             int* __restrict__ bsum,
                                             float* __restrict__ dis, int n) {
    __shared__ int sm[256];
    int base = blockIdx.x * 2048 + threadIdx.x * 8;
    int v[8];
    int s = 0;
#pragma unroll
    for (int j = 0; j < 8; ++j) {
        int i = base + j;
        int c = (i < n) ? counts[i] : 0;
        v[j] = c;
        s += c;
        if (i < n) dis[i] = rsqrtf((float)(c + 1));  // +1: self-loop
    }
    sm[threadIdx.x] = s;
    __syncthreads();
    for (int off = 1; off < 256; off <<= 1) {
        int t = (threadIdx.x >= off) ? sm[threadIdx.x - off] : 0;
        __syncthreads();
        sm[threadIdx.x] += t;
        __syncthreads();
    }
    int excl = sm[threadIdx.x] - s;
#pragma unroll
    for (int j = 0; j < 8; ++j) {
        int i = base + j;
        if (i < n) row_ptr[i] = excl;
        excl += v[j];
    }
    if (threadIdx.x == 255) bsum[blockIdx.x] = sm[255];
}

// Stage B: single-wave exclusive scan of block sums (nb <= 64).
__global__ __launch_bounds__(64) void scanB(int* __restrict__ bsum, int nb) {
    __shared__ int sm[64];
    int v = (threadIdx.x < nb) ? bsum[threadIdx.x] : 0;
    sm[threadIdx.x] = v;
    __syncthreads();
    for (int off = 1; off < 64; off <<= 1) {
        int t = (threadIdx.x >= off) ? sm[threadIdx.x - off] : 0;
        __syncthreads();
        sm[threadIdx.x] += t;
        __syncthreads();
    }
    if (threadIdx.x < nb) bsum[threadIdx.x] = sm[threadIdx.x] - v;
}

// Stage C: add block offsets, copy to cursor, write row_ptr[n] = E.
__global__ void scanC(int* __restrict__ row_ptr, int* __restrict__ cursor,
                      const int* __restrict__ bsum, int n, int E) {
    int i = blockIdx.x * 256 + threadIdx.x;
    if (i < n) {
        int v = row_ptr[i] + bsum[i >> 11];
        row_ptr[i] = v;
        cursor[i] = v;
    }
    if (i == 0) row_ptr[n] = E;
}

// CSR fill; stores (src, dis[src]) packed so agg does a single 8B load per edge.
__global__ void fill_kernel(const int* __restrict__ src, const int* __restrict__ dst,
                            int* __restrict__ cursor, const float* __restrict__ dis,
                            uint2* __restrict__ edge_sw, int E) {
    int e = blockIdx.x * 256 + threadIdx.x;
    if (e < E) {
        int s = src[e];
        int pos = atomicAdd(&cursor[dst[e]], 1);
        edge_sw[pos] = make_uint2((unsigned)s, __float_as_uint(dis[s]));
    }
}

// A[i] = dis[i] * ( sum_{s in in(i)} dis[s]*X[s] + dis[i]*X[i] )
// 256 threads = 64 nodes x 4 lanes; each lane handles NF4 float4 chunks.
// Block's CSR edge range is contiguous -> staged ONCE into LDS, shared by all
// feature chunks (kills the 24x redundant edge reads of the old layout).
template <int NF4>  // float4 chunks per thread; feature width = NF4*16 floats
__global__ __launch_bounds__(256) void agg_kernel(const float* __restrict__ X,
                                                  const float* __restrict__ dis,
                                                  const int* __restrict__ row_ptr,
                                                  const uint2* __restrict__ edge_sw,
                                                  float* __restrict__ A, int n) {
    constexpr int ECAP = 2048;  // avg block edges ~1024; overflow guarded below
    __shared__ uint2 eb[ECAP];
    int i0 = blockIdx.x * 64;
    int iend = min(i0 + 64, n);
    int e0 = row_ptr[i0];
    int stage = min(row_ptr[iend] - e0, ECAP);
    for (int idx = threadIdx.x; idx < stage; idx += 256)
        eb[idx] = edge_sw[e0 + idx];
    __syncthreads();
    int r = threadIdx.x >> 2, c = threadIdx.x & 3;
    int i = i0 + r;
    if (i >= n) return;
    const float4* X4 = (const float4*)X;
    float di = dis[i];
    size_t base = (size_t)i * (NF4 * 4) + c * NF4;
    float4 acc[NF4];
#pragma unroll
    for (int j = 0; j < NF4; ++j) {
        float4 x = X4[base + j];
        acc[j] = make_float4(di * x.x, di * x.y, di * x.z, di * x.w);
    }
    int re0 = row_ptr[i], re1 = row_ptr[i + 1];
    for (int e = re0; e < re1; ++e) {
        int le = e - e0;
        uint2 ew = (le < stage) ? eb[le] : edge_sw[e];
        int s = (int)ew.x;
        float ds = __uint_as_float(ew.y);
        size_t sb = (size_t)s * (NF4 * 4) + c * NF4;
#pragma unroll
        for (int j = 0; j < NF4; ++j) {
            float4 xs = X4[sb + j];
            acc[j].x += ds * xs.x; acc[j].y += ds * xs.y;
            acc[j].z += ds * xs.z; acc[j].w += ds * xs.w;
        }
    }
#pragma unroll
    for (int j = 0; j < NF4; ++j) {
        float4 o;
        o.x = di * acc[j].x; o.y = di * acc[j].y;
        o.z = di * acc[j].z; o.w = di * acc[j].w;
        ((float4*)A)[base + j] = o;
    }
}

// Xn[i,f] = leaky( sum_k A[i,k]*W[k,f] + b[f] ),  W row-major [K,96], out width 96.
// 192 threads = 24 f-quads x 8 row-groups; 64 nodes/block, 8 rows x 4 f each.
// A-tile in LDS (24.6 KB -> 6 blocks/CU); W read from global (wave-broadcast,
// L1/L2-resident) so LDS stays small and occupancy high.
template <int K>
__global__ __launch_bounds__(192) void gemm_act_kernel(const float* __restrict__ A,
                                                       const float* __restrict__ W,
                                                       const float* __restrict__ b,
                                                       float* __restrict__ Xn, int n) {
    constexpr int KQ = K / 4;
    __shared__ __align__(16) float4 Al[64 * KQ];
    int tid = threadIdx.x;
    int i0 = blockIdx.x * 64;
    for (int idx = tid; idx < 64 * KQ; idx += 192) {
        int gi = i0 + idx / KQ;
        Al[idx] = (gi < n) ? ((const float4*)A)[(size_t)i0 * KQ + idx]
                           : make_float4(0.f, 0.f, 0.f, 0.f);
    }
    __syncthreads();
    int fq = tid % 24;  // output float4 column
    int g = tid / 24;   // row group: rows g*8 .. g*8+7
    const float4* W4 = (const float4*)W;  // W4[k*24 + fq]
    float4 bb = ((const float4*)b)[fq];
    float4 acc[8];
#pragma unroll
    for (int r = 0; r < 8; ++r) acc[r] = bb;
    for (int kc = 0; kc < K; kc += 8) {
        float4 w[8];
#pragma unroll
        for (int kk = 0; kk < 8; ++kk) w[kk] = W4[(size_t)(kc + kk) * 24 + fq];
#pragma unroll
        for (int r = 0; r < 8; ++r) {
            const float4* ar = &Al[(g * 8 + r) * KQ + (kc >> 2)];
#pragma unroll
            for (int k4 = 0; k4 < 2; ++k4) {
                float4 a = ar[k4];
                float4 w0 = w[4 * k4 + 0], w1 = w[4 * k4 + 1];
                float4 w2 = w[4 * k4 + 2], w3 = w[4 * k4 + 3];
                acc[r].x += a.x * w0.x + a.y * w1.x + a.z * w2.x + a.w * w3.x;
                acc[r].y += a.x * w0.y + a.y * w1.y + a.z * w2.y + a.w * w3.y;
                acc[r].z += a.x * w0.z + a.y * w1.z + a.z * w2.z + a.w * w3.z;
                acc[r].w += a.x * w0.w + a.y * w1.w + a.z * w2.w + a.w * w3.w;
            }
        }
    }
#pragma unroll
    for (int r = 0; r < 8; ++r) {
        int gi = i0 + g * 8 + r;
        if (gi < n) {
            float4 o;
            o.x = LEAKY(acc[r].x); o.y = LEAKY(acc[r].y);
            o.z = LEAKY(acc[r].z); o.w = LEAKY(acc[r].w);
            ((float4*)Xn)[(size_t)gi * 24 + fq] = o;
        }
    }
}

__device__ __forceinline__ int lower_bound(const int* b, int n, int v) {
    int lo = 0, hi = n;
    while (lo < hi) {
        int m = (lo + hi) >> 1;
        if (b[m] < v) lo = m + 1; else hi = m;
    }
    return lo;
}

// grid = G*8, block = 96. Chunked per-graph partial max/sum.
__global__ void pool_partial(const float* __restrict__ X, const int* __restrict__ batch,
                             float* __restrict__ pmax, float* __restrict__ psum, int n) {
    int g = blockIdx.x / 8, ch = blockIdx.x % 8;
    int f = threadIdx.x;
    int s = lower_bound(batch, n, g), e = lower_bound(batch, n, g + 1);
    int len = e - s;
    int cs = s + (int)((long)len * ch / 8);
    int ce = s + (int)((long)len * (ch + 1) / 8);
    float mx = -INFINITY, sm = 0.f;
    for (int i = cs; i < ce; ++i) {
        float v = X[(size_t)i * 96 + f];
        mx = fmaxf(mx, v);
        sm += v;
    }
    pmax[(size_t)blockIdx.x * 96 + f] = mx;
    psum[(size_t)blockIdx.x * 96 + f] = sm;
}

__global__ void pool_reduce(const float* __restrict__ pmax, const float* __restrict__ psum,
                            const int* __restrict__ batch, float* __restrict__ pooled, int n) {
    int g = blockIdx.x, f = threadIdx.x;
    float mx = -INFINITY, sm = 0.f;
    for (int c = 0; c < 8; ++c) {
        mx = fmaxf(mx, pmax[(size_t)(g * 8 + c) * 96 + f]);
        sm += psum[(size_t)(g * 8 + c) * 96 + f];
    }
    int s = lower_bound(batch, n, g), e = lower_bound(batch, n, g + 1);
    float cnt = fmaxf((float)(e - s), 1.f);
    pooled[g * 192 + f] = mx;
    pooled[g * 192 + 96 + f] = sm / cnt;
}

// out[g] = leaky(pooled[g]@Wo1 + bo1) @ Wo2 + bo2
__global__ void mlp_kernel(const float* __restrict__ pooled, const float* __restrict__ Wo1,
                           const float* __restrict__ bo1, const float* __restrict__ Wo2,
                           const float* __restrict__ bo2, float* __restrict__ out) {
    __shared__ float sh[96];
    int g = blockIdx.x, f = threadIdx.x;
    float acc = bo1[f];
    for (int k = 0; k < 192; ++k) acc += pooled[g * 192 + k] * Wo1[k * 96 + f];
    float a = LEAKY(acc);
    sh[f] = a * Wo2[f];
    __syncthreads();
    if (f == 0) {
        float sacc = 0.f;
        for (int k = 0; k < 96; ++k) sacc += sh[k];
        out[g] = sacc + bo2[0];
    }
}

extern "C" void kernel_launch(void* const* d_in, const int* in_sizes, int n_in,
                              void* d_out, int out_size, void* d_ws, size_t ws_size,
                              hipStream_t stream) {
    const float* x      = (const float*)d_in[0];
    const int*   eidx   = (const int*)d_in[1];
    const int*   batch  = (const int*)d_in[2];
    const float* W_init = (const float*)d_in[3];
    const float* b_init = (const float*)d_in[4];
    const float* W1 = (const float*)d_in[5];  const float* b1 = (const float*)d_in[6];
    const float* W2 = (const float*)d_in[7];  const float* b2 = (const float*)d_in[8];
    const float* W3 = (const float*)d_in[9];  const float* b3 = (const float*)d_in[10];
    const float* W4 = (const float*)d_in[11]; const float* b4 = (const float*)d_in[12];
    const float* Wo1 = (const float*)d_in[13]; const float* bo1 = (const float*)d_in[14];
    const float* Wo2 = (const float*)d_in[15]; const float* bo2 = (const float*)d_in[16];
    float* out = (float*)d_out;

    const int N = in_sizes[2];
    const int E = in_sizes[1] / 2;
    const int G = out_size;
    const int* src = eidx;
    const int* dst = eidx + E;

    char* ws = (char*)d_ws;
    size_t off = 0;
    auto alloc = [&](size_t bytes) {
        size_t o = off;
        off += (bytes + 255) & ~(size_t)255;
        return o;
    };
    float* dis     = (float*)(ws + alloc((size_t)N * 4));
    int*   counts  = (int*)(ws + alloc((size_t)N * 4));
    int*   row_ptr = (int*)(ws + alloc((size_t)(N + 1) * 4));
    int*   cursor  = (int*)(ws + alloc((size_t)N * 4));
    int*   bsum    = (int*)(ws + alloc(64 * 4));
    uint2* edge_sw = (uint2*)(ws + alloc((size_t)E * 8));
    float* B1      = (float*)(ws + alloc((size_t)N * 96 * 4));
    float* B2      = (float*)(ws + alloc((size_t)N * 96 * 4));
    float* pmax    = (float*)(ws + alloc((size_t)G * 8 * 96 * 4));
    float* psum    = (float*)(ws + alloc((size_t)G * 8 * 96 * 4));
    float* pooled  = (float*)(ws + alloc((size_t)G * 192 * 4));
    (void)ws_size; (void)n_in;

    const int nbScan = (N + 2047) / 2048;
    const int nbNode = (N + 63) / 64;

    zero_i32<<<(N + 255) / 256, 256, 0, stream>>>(counts, N);
    count_kernel<<<(E + 255) / 256, 256, 0, stream>>>(dst, counts, E);
    scanA<<<nbScan, 256, 0, stream>>>(counts, row_ptr, bsum, dis, N);
    scanB<<<1, 64, 0, stream>>>(bsum, nbScan);
    scanC<<<(N + 255) / 256, 256, 0, stream>>>(row_ptr, cursor, bsum, N, E);
    fill_kernel<<<(E + 255) / 256, 256, 0, stream>>>(src, dst, cursor, dis, edge_sw, E);

    // Layer 0: aggregate 16-wide input, then 16x96 GEMM.
    agg_kernel<1><<<nbNode, 256, 0, stream>>>(x, dis, row_ptr, edge_sw, B2, N);
    gemm_act_kernel<16><<<nbNode, 192, 0, stream>>>(B2, W_init, b_init, B1, N);

    const float* Ws[4] = {W1, W2, W3, W4};
    const float* bs[4] = {b1, b2, b3, b4};
    for (int l = 0; l < 4; ++l) {
        agg_kernel<6><<<nbNode, 256, 0, stream>>>(B1, dis, row_ptr, edge_sw, B2, N);
        gemm_act_kernel<96><<<nbNode, 192, 0, stream>>>(B2, Ws[l], bs[l], B1, N);
    }

    pool_partial<<<G * 8, 96, 0, stream>>>(B1, batch, pmax, psum, N);
    pool_reduce<<<G, 96, 0, stream>>>(pmax, psum, batch, pooled, N);
    mlp_kernel<<<G, 96, 0, stream>>>(pooled, Wo1, bo1, Wo2, bo2, out);
}